// Round 1
// baseline (364.908 us; speedup 1.0000x reference)
//
#include <hip/hip_runtime.h>
#include <hip/hip_bf16.h>
#include <math.h>

// ---------------------------------------------------------------------------
// KAN 2-layer forward.
//   layer1: x(128,3072) -> h(128,256), coef1(256,3072,8), sb1/ssp1(256,3072)
//   selu
//   layer2: h(128,256) -> out(128,10), coef2(10,256,8), sb2/ssp2(10,256)
// Basis: cardinal cubic B-spline on uniform extended grid [-2.2, 2.2], h=0.4.
// ---------------------------------------------------------------------------

#define B_DIM   128
#define IN1     3072
#define OUT1    256
#define NB      8     // num + k
#define OUT2    10

// cardinal cubic B-spline basis (8 funcs) + silu, closed form.
// Verified equivalent to the Cox-de Boor recursion of the reference
// (uniform knots -> translated cardinal B-splines; edge funcs simply dropped).
__device__ __forceinline__ void basis_silu(float x, float w[8], float& sil) {
    sil = x / (1.0f + __expf(-x));
    float u  = (x + 2.2f) * 2.5f;
    float uf = floorf(u);
    int   j  = (int)uf;
    float t  = u - uf;
    float omt = 1.0f - t;
    float t2 = t * t, t3 = t2 * t;
    float w0 = omt * omt * omt * (1.0f / 6.0f);
    float w1 = (3.0f * t3 - 6.0f * t2 + 4.0f) * (1.0f / 6.0f);
    float w2 = (-3.0f * t3 + 3.0f * t2 + 3.0f * t + 1.0f) * (1.0f / 6.0f);
    float w3 = t3 * (1.0f / 6.0f);
    bool valid = (u >= 0.0f) && (u < 11.0f);
#pragma unroll
    for (int g = 0; g < 8; ++g) {
        int m = g - j + 3;                 // which of w0..w3 lands on basis g
        float v = (m == 0) ? w0 : (m == 1) ? w1 : (m == 2) ? w2 : (m == 3) ? w3 : 0.0f;
        w[g] = valid ? v : 0.0f;
    }
}

__device__ __forceinline__ float selu_f(float x) {
    const float scale = 1.0507009873554805f;
    const float alpha = 1.6732632423543772f;
    return (x > 0.0f) ? scale * x : scale * alpha * (__expf(x) - 1.0f);
}

// ---------------------------------------------------------------------------
// Kernel T: transpose x (128,3072) -> xT (3072,128) for coalesced b-major reads
// ---------------------------------------------------------------------------
__global__ __launch_bounds__(256) void ktranspose(const float* __restrict__ x,
                                                  float* __restrict__ xT) {
    __shared__ float t[32][33];
    int bx = blockIdx.x;              // i-tile 0..95
    int by = blockIdx.y;              // b-tile 0..3
    int tx = threadIdx.x;             // 0..31
    int ty = threadIdx.y;             // 0..7
#pragma unroll
    for (int k = 0; k < 4; ++k) {
        int b = by * 32 + ty + k * 8;
        int i = bx * 32 + tx;
        t[ty + k * 8][tx] = x[b * IN1 + i];
    }
    __syncthreads();
#pragma unroll
    for (int k = 0; k < 4; ++k) {
        int i = bx * 32 + ty + k * 8;
        int b = by * 32 + tx;
        xT[i * B_DIM + b] = t[tx][ty + k * 8];
    }
}

// ---------------------------------------------------------------------------
// Kernel Z: zero h accumulator (must run every call: atomics accumulate)
// ---------------------------------------------------------------------------
__global__ __launch_bounds__(256) void kzero(float* __restrict__ h) {
    h[blockIdx.x * 256 + threadIdx.x] = 0.0f;
}

// ---------------------------------------------------------------------------
// Kernel G: layer-1 GEMM.  C(128,256) += A(128, K=27648) * W(K, 256)
//   A generated on the fly from xT (basis+silu), W fused from coef1*ssp1 / sb1.
//   BM=BN=64, 64 threads, TM=TN=8, K-split into 128 chunks of 24 i (216 k).
//   Stages of SI=4 i (KP=36 k) through LDS; f32 atomicAdd epilogue into h.
// ---------------------------------------------------------------------------
#define KCI 24                // i's per block
#define SI  4                 // i's per LDS stage
#define KP  (SI * 9)          // 36 k per stage

__global__ __launch_bounds__(64) void kan_gemm1(const float* __restrict__ xT,
                                                const float* __restrict__ coef1,
                                                const float* __restrict__ sb1,
                                                const float* __restrict__ ssp1,
                                                float* __restrict__ h) {
    __shared__ float At[KP][64];
    __shared__ float Wt[KP][64];

    const int tid  = threadIdx.x;          // 0..63
    const int tile = blockIdx.x;           // 0..7
    const int kc   = blockIdx.y;           // 0..127
    const int mt = tile >> 2, nt = tile & 3;
    const int b0 = mt * 64, o0 = nt * 64;
    const int i_base = kc * KCI;
    const int tx = tid & 7, ty = tid >> 3;

    float acc[8][8];
#pragma unroll
    for (int r = 0; r < 8; ++r)
#pragma unroll
        for (int c = 0; c < 8; ++c) acc[r][c] = 0.0f;

    const int og = o0 + tid;               // this thread's o for W staging

    for (int s = 0; s < KCI / SI; ++s) {
        const int i0 = i_base + s * SI;

        // ---- stage A: thread -> b = b0+tid, loop 4 i's ----
#pragma unroll
        for (int p = 0; p < SI; ++p) {
            float xv = xT[(i0 + p) * B_DIM + b0 + tid];
            float w[8], sil;
            basis_silu(xv, w, sil);
#pragma unroll
            for (int m = 0; m < 8; ++m) At[p * 9 + m][tid] = w[m];
            At[p * 9 + 8][tid] = sil;
        }

        // ---- stage W: thread -> o = og, loop 4 i's ----
#pragma unroll
        for (int p = 0; p < SI; ++p) {
            const float* cp = coef1 + ((size_t)og * IN1 + (i0 + p)) * NB;
            float4 c0 = *reinterpret_cast<const float4*>(cp);
            float4 c1 = *reinterpret_cast<const float4*>(cp + 4);
            float sspv = ssp1[og * IN1 + i0 + p];
            float sbv  = sb1[og * IN1 + i0 + p];
            Wt[p * 9 + 0][tid] = c0.x * sspv;
            Wt[p * 9 + 1][tid] = c0.y * sspv;
            Wt[p * 9 + 2][tid] = c0.z * sspv;
            Wt[p * 9 + 3][tid] = c0.w * sspv;
            Wt[p * 9 + 4][tid] = c1.x * sspv;
            Wt[p * 9 + 5][tid] = c1.y * sspv;
            Wt[p * 9 + 6][tid] = c1.z * sspv;
            Wt[p * 9 + 7][tid] = c1.w * sspv;
            Wt[p * 9 + 8][tid] = sbv;
        }
        __syncthreads();

        // ---- MAC: 36 k, 8x8 outer product per thread ----
#pragma unroll 6
        for (int k = 0; k < KP; ++k) {
            float4 a0 = *reinterpret_cast<const float4*>(&At[k][tx * 8]);
            float4 a1 = *reinterpret_cast<const float4*>(&At[k][tx * 8 + 4]);
            float4 w0 = *reinterpret_cast<const float4*>(&Wt[k][ty * 8]);
            float4 w1 = *reinterpret_cast<const float4*>(&Wt[k][ty * 8 + 4]);
            float av[8] = {a0.x, a0.y, a0.z, a0.w, a1.x, a1.y, a1.z, a1.w};
            float wv[8] = {w0.x, w0.y, w0.z, w0.w, w1.x, w1.y, w1.z, w1.w};
#pragma unroll
            for (int r = 0; r < 8; ++r)
#pragma unroll
                for (int c = 0; c < 8; ++c)
                    acc[r][c] = fmaf(av[r], wv[c], acc[r][c]);
        }
        __syncthreads();
    }

    // ---- epilogue: accumulate partial tile into h ----
#pragma unroll
    for (int r = 0; r < 8; ++r)
#pragma unroll
        for (int c = 0; c < 8; ++c)
            atomicAdd(&h[(b0 + tx * 8 + r) * OUT1 + (o0 + ty * 8 + c)], acc[r][c]);
}

// ---------------------------------------------------------------------------
// Kernel L2: selu(h) then layer-2 KAN.  One block per batch row b.
// ---------------------------------------------------------------------------
__global__ __launch_bounds__(256) void kan_layer2(const float* __restrict__ h,
                                                  const float* __restrict__ coef2,
                                                  const float* __restrict__ sb2,
                                                  const float* __restrict__ ssp2,
                                                  float* __restrict__ out) {
    const int b = blockIdx.x;
    const int i = threadIdx.x;               // 0..255
    float hv = h[b * OUT1 + i];
    float sh = selu_f(hv);
    float w[8], sil;
    basis_silu(sh, w, sil);

    float accs[OUT2];
#pragma unroll
    for (int o = 0; o < OUT2; ++o) {
        const float* cp = coef2 + ((size_t)o * OUT1 + i) * NB;
        float4 c0 = *reinterpret_cast<const float4*>(cp);
        float4 c1 = *reinterpret_cast<const float4*>(cp + 4);
        float dot = w[0] * c0.x + w[1] * c0.y + w[2] * c0.z + w[3] * c0.w +
                    w[4] * c1.x + w[5] * c1.y + w[6] * c1.z + w[7] * c1.w;
        accs[o] = sb2[o * OUT1 + i] * sil + ssp2[o * OUT1 + i] * dot;
    }

    __shared__ float red[4][OUT2];
    const int lane = i & 63, wv = i >> 6;
#pragma unroll
    for (int o = 0; o < OUT2; ++o) {
        float v = accs[o];
#pragma unroll
        for (int off = 32; off >= 1; off >>= 1) v += __shfl_xor(v, off, 64);
        if (lane == 0) red[wv][o] = v;
    }
    __syncthreads();
    if (i < OUT2)
        out[b * OUT2 + i] = red[0][i] + red[1][i] + red[2][i] + red[3][i];
}

// ---------------------------------------------------------------------------
extern "C" void kernel_launch(void* const* d_in, const int* in_sizes, int n_in,
                              void* d_out, int out_size, void* d_ws, size_t ws_size,
                              hipStream_t stream) {
    const float* x     = (const float*)d_in[0];
    const float* coef1 = (const float*)d_in[1];
    const float* sb1   = (const float*)d_in[2];
    const float* ssp1  = (const float*)d_in[3];
    const float* coef2 = (const float*)d_in[4];
    const float* sb2   = (const float*)d_in[5];
    const float* ssp2  = (const float*)d_in[6];
    float* out = (float*)d_out;

    float* xT = (float*)d_ws;                                   // 3072*128 f32 = 1.5 MB
    float* h  = (float*)((char*)d_ws + (size_t)IN1 * B_DIM * 4); // 128*256 f32 = 128 KB

    ktranspose<<<dim3(96, 4), dim3(32, 8), 0, stream>>>(x, xT);
    kzero<<<128, 256, 0, stream>>>(h);
    kan_gemm1<<<dim3(8, IN1 / KCI), 64, 0, stream>>>(xT, coef1, sb1, ssp1, h);
    kan_layer2<<<B_DIM, 256, 0, stream>>>(h, coef2, sb2, ssp2, out);
}

// Round 2
// 48.532 us; speedup vs baseline: 7.5190x; 7.5190x over previous
//
#include <hip/hip_runtime.h>
#include <hip/hip_bf16.h>
#include <math.h>

// ---------------------------------------------------------------------------
// KAN 2-layer forward, bf16-MFMA formulation.
//   layer1 GEMM: C(128,256) = A(128,K) * W(K,256), K = 3072 * 12 (padded)
//     per input i: k-slots m=0..7 spline basis, m=8 silu, m=9..11 zero pad
//     A from x on the fly; W = {coef1*ssp1, sb1} converted to bf16 on the fly
//   K-split into 128 chunks of 24 i; bf16 partials in ws; reduce fused with
//   selu + layer2 (tiny: 256->10).
// ---------------------------------------------------------------------------

#define B_DIM   128
#define IN1     3072
#define OUT1    256
#define NB      8
#define OUT2    10

#define KC      24            // i per k-chunk (128 chunks)
#define NCHUNK  (IN1 / KC)
#define SI      8             // i per LDS stage
#define LDP     104           // padded row length (ushorts) for 96 k

typedef short  bf16x8 __attribute__((ext_vector_type(8)));
typedef float  f32x4  __attribute__((ext_vector_type(4)));
typedef unsigned short ushort_t;

__device__ __forceinline__ ushort_t f2bf(float f) {
    union { float f; unsigned int u; } v; v.f = f;
    unsigned int u = v.u;
    return (ushort_t)((u + 0x7FFFu + ((u >> 16) & 1u)) >> 16);   // RNE
}
__device__ __forceinline__ float bf2f(ushort_t h) {
    union { float f; unsigned int u; } v; v.u = ((unsigned int)h) << 16;
    return v.f;
}

// cardinal cubic B-spline basis (8 funcs) + silu, closed form (== Cox-de Boor
// recursion of the reference on the uniform extended grid [-2.2,2.2], h=0.4).
__device__ __forceinline__ void basis_silu(float x, float w[8], float& sil) {
    sil = x / (1.0f + __expf(-x));
    float u  = (x + 2.2f) * 2.5f;
    float uf = floorf(u);
    int   j  = (int)uf;
    float t  = u - uf;
    float omt = 1.0f - t;
    float t2 = t * t, t3 = t2 * t;
    float w0 = omt * omt * omt * (1.0f / 6.0f);
    float w1 = (3.0f * t3 - 6.0f * t2 + 4.0f) * (1.0f / 6.0f);
    float w2 = (-3.0f * t3 + 3.0f * t2 + 3.0f * t + 1.0f) * (1.0f / 6.0f);
    float w3 = t3 * (1.0f / 6.0f);
    bool valid = (u >= 0.0f) && (u < 11.0f);
#pragma unroll
    for (int g = 0; g < 8; ++g) {
        int m = g - j + 3;
        float v = (m == 0) ? w0 : (m == 1) ? w1 : (m == 2) ? w2 : (m == 3) ? w3 : 0.0f;
        w[g] = valid ? v : 0.0f;
    }
}

__device__ __forceinline__ float selu_f(float x) {
    const float scale = 1.0507009873554805f;
    const float alpha = 1.6732632423543772f;
    return (x > 0.0f) ? scale * x : scale * alpha * (__expf(x) - 1.0f);
}

// ---------------------------------------------------------------------------
// Kernel T: transpose x (128,3072) -> xT (3072,128)
// ---------------------------------------------------------------------------
__global__ __launch_bounds__(256) void ktranspose(const float* __restrict__ x,
                                                  float* __restrict__ xT) {
    __shared__ float t[32][33];
    int bx = blockIdx.x, by = blockIdx.y;
    int tx = threadIdx.x, ty = threadIdx.y;
#pragma unroll
    for (int k = 0; k < 4; ++k)
        t[ty + k * 8][tx] = x[(by * 32 + ty + k * 8) * IN1 + bx * 32 + tx];
    __syncthreads();
#pragma unroll
    for (int k = 0; k < 4; ++k)
        xT[(bx * 32 + ty + k * 8) * B_DIM + by * 32 + tx] = t[tx][ty + k * 8];
}

// ---------------------------------------------------------------------------
// Kernel G: bf16 MFMA GEMM chunk.  grid = (4 n-tiles, 128 k-chunks), 256 thr.
// Block output: 128 x 64.  Wave w covers n-cols [o0+16w, o0+16w+16), 8 m-tiles.
// ---------------------------------------------------------------------------
__global__ __launch_bounds__(256) void kan_gemm_mfma(const float* __restrict__ xT,
                                                     const float* __restrict__ coef1,
                                                     const float* __restrict__ sb1,
                                                     const float* __restrict__ ssp1,
                                                     ushort_t* __restrict__ partial) {
    __shared__ ushort_t Al[B_DIM][LDP];   // A tile: [b][96 k] (+pad)
    __shared__ ushort_t Bl[64][LDP];      // W tile: [o][96 k] (+pad)

    const int tid   = threadIdx.x;
    const int w     = tid >> 6;
    const int l     = tid & 63;
    const int o0    = blockIdx.x * 64;
    const int chunk = blockIdx.y;
    const int i_base = chunk * KC;

    f32x4 acc[8];
#pragma unroll
    for (int mt = 0; mt < 8; ++mt) acc[mt] = (f32x4){0.f, 0.f, 0.f, 0.f};

    const int row16 = l & 15;
    const int kg    = (l >> 4) * 8;

    for (int s = 0; s < KC / SI; ++s) {
        const int i0 = i_base + s * SI;

        // ---- stage A: 256 thr cover 128 b x 8 i; thread -> b, 4 i's ----
        {
            const int b  = tid & 127;
            const int ih = (tid >> 7) * 4;
#pragma unroll
            for (int p = 0; p < 4; ++p) {
                const int ii = ih + p;
                float xv = xT[(size_t)(i0 + ii) * B_DIM + b];
                float bs[8], sil;
                basis_silu(xv, bs, sil);
                ushort4 pa, pb, pc;
                pa.x = f2bf(bs[0]); pa.y = f2bf(bs[1]); pa.z = f2bf(bs[2]); pa.w = f2bf(bs[3]);
                pb.x = f2bf(bs[4]); pb.y = f2bf(bs[5]); pb.z = f2bf(bs[6]); pb.w = f2bf(bs[7]);
                pc.x = f2bf(sil);   pc.y = 0;           pc.z = 0;           pc.w = 0;
                *reinterpret_cast<ushort4*>(&Al[b][ii * 12 + 0]) = pa;
                *reinterpret_cast<ushort4*>(&Al[b][ii * 12 + 4]) = pb;
                *reinterpret_cast<ushort4*>(&Al[b][ii * 12 + 8]) = pc;
            }
        }
        // ---- stage W: 256 thr cover 64 o x 8 i; thread -> o, 2 i's ----
        {
            const int ol = tid >> 2;
            const int o  = o0 + ol;
#pragma unroll
            for (int q = 0; q < 2; ++q) {
                const int ii = (tid & 3) * 2 + q;
                const int i  = i0 + ii;
                const float* cp = coef1 + ((size_t)o * IN1 + i) * NB;
                float4 c0 = *reinterpret_cast<const float4*>(cp);
                float4 c1 = *reinterpret_cast<const float4*>(cp + 4);
                float sspv = ssp1[(size_t)o * IN1 + i];
                float sbv  = sb1[(size_t)o * IN1 + i];
                ushort4 pa, pb, pc;
                pa.x = f2bf(c0.x * sspv); pa.y = f2bf(c0.y * sspv);
                pa.z = f2bf(c0.z * sspv); pa.w = f2bf(c0.w * sspv);
                pb.x = f2bf(c1.x * sspv); pb.y = f2bf(c1.y * sspv);
                pb.z = f2bf(c1.z * sspv); pb.w = f2bf(c1.w * sspv);
                pc.x = f2bf(sbv);         pc.y = 0; pc.z = 0; pc.w = 0;
                *reinterpret_cast<ushort4*>(&Bl[ol][ii * 12 + 0]) = pa;
                *reinterpret_cast<ushort4*>(&Bl[ol][ii * 12 + 4]) = pb;
                *reinterpret_cast<ushort4*>(&Bl[ol][ii * 12 + 8]) = pc;
            }
        }
        __syncthreads();

        // ---- MFMA: 3 k-steps of 32, 8 m-tiles ----
#pragma unroll
        for (int ks = 0; ks < 3; ++ks) {
            bf16x8 bfrag = *reinterpret_cast<const bf16x8*>(&Bl[w * 16 + row16][ks * 32 + kg]);
#pragma unroll
            for (int mt = 0; mt < 8; ++mt) {
                bf16x8 afrag = *reinterpret_cast<const bf16x8*>(&Al[mt * 16 + row16][ks * 32 + kg]);
                acc[mt] = __builtin_amdgcn_mfma_f32_16x16x32_bf16(afrag, bfrag, acc[mt], 0, 0, 0);
            }
        }
        __syncthreads();
    }

    // ---- epilogue: bf16 partial [chunk][b][o] ----
    const size_t base = (size_t)chunk * (B_DIM * OUT1);
    const int col   = o0 + w * 16 + row16;
    const int rbase = (l >> 4) * 4;
#pragma unroll
    for (int mt = 0; mt < 8; ++mt) {
#pragma unroll
        for (int r = 0; r < 4; ++r) {
            const int b = mt * 16 + rbase + r;
            partial[base + (size_t)b * OUT1 + col] = f2bf(acc[mt][r]);
        }
    }
}

// ---------------------------------------------------------------------------
// Kernel R: reduce partials -> h, then selu + layer2.  One block per b.
// ---------------------------------------------------------------------------
__global__ __launch_bounds__(256) void kan_reduce_l2(const ushort_t* __restrict__ partial,
                                                     const float* __restrict__ coef2,
                                                     const float* __restrict__ sb2,
                                                     const float* __restrict__ ssp2,
                                                     float* __restrict__ out) {
    const int b = blockIdx.x;
    const int t = threadIdx.x;               // t = o1 (h index), 0..255
    const ushort_t* pp = partial + (size_t)b * OUT1 + t;
    float sum = 0.0f;
#pragma unroll 8
    for (int c = 0; c < NCHUNK; ++c)
        sum += bf2f(pp[(size_t)c * (B_DIM * OUT1)]);

    float sh = selu_f(sum);
    float w8[8], sil;
    basis_silu(sh, w8, sil);

    float accs[OUT2];
#pragma unroll
    for (int o = 0; o < OUT2; ++o) {
        const float* cp = coef2 + ((size_t)o * OUT1 + t) * NB;
        float4 c0 = *reinterpret_cast<const float4*>(cp);
        float4 c1 = *reinterpret_cast<const float4*>(cp + 4);
        float dot = w8[0] * c0.x + w8[1] * c0.y + w8[2] * c0.z + w8[3] * c0.w +
                    w8[4] * c1.x + w8[5] * c1.y + w8[6] * c1.z + w8[7] * c1.w;
        accs[o] = sb2[o * OUT1 + t] * sil + ssp2[o * OUT1 + t] * dot;
    }

    __shared__ float red[4][OUT2];
    const int lane = t & 63, wv = t >> 6;
#pragma unroll
    for (int o = 0; o < OUT2; ++o) {
        float v = accs[o];
#pragma unroll
        for (int off = 32; off >= 1; off >>= 1) v += __shfl_xor(v, off, 64);
        if (lane == 0) red[wv][o] = v;
    }
    __syncthreads();
    if (t < OUT2)
        out[b * OUT2 + t] = red[0][t] + red[1][t] + red[2][t] + red[3][t];
}

// ---------------------------------------------------------------------------
extern "C" void kernel_launch(void* const* d_in, const int* in_sizes, int n_in,
                              void* d_out, int out_size, void* d_ws, size_t ws_size,
                              hipStream_t stream) {
    const float* x     = (const float*)d_in[0];
    const float* coef1 = (const float*)d_in[1];
    const float* sb1   = (const float*)d_in[2];
    const float* ssp1  = (const float*)d_in[3];
    const float* coef2 = (const float*)d_in[4];
    const float* sb2   = (const float*)d_in[5];
    const float* ssp2  = (const float*)d_in[6];
    float* out = (float*)d_out;

    float*    xT      = (float*)d_ws;                                  // 1.5 MB
    ushort_t* partial = (ushort_t*)((char*)d_ws + (size_t)IN1 * B_DIM * 4); // 8.4 MB

    ktranspose<<<dim3(96, 4), dim3(32, 8), 0, stream>>>(x, xT);
    kan_gemm_mfma<<<dim3(4, NCHUNK), 256, 0, stream>>>(xT, coef1, sb1, ssp1, partial);
    kan_reduce_l2<<<B_DIM, 256, 0, stream>>>(partial, coef2, sb2, ssp2, out);
}

// Round 3
// 44.336 us; speedup vs baseline: 8.2306x; 1.0946x over previous
//
#include <hip/hip_runtime.h>
#include <hip/hip_bf16.h>
#include <math.h>

// ---------------------------------------------------------------------------
// KAN 2-layer forward, bf16-MFMA, single-shot split-K blocks.
//   layer1 GEMM: C(128,256) = A(128,K) * W(K,256), K = 3072 * 12 (padded)
//     per input i: k-slots 0..7 = cubic B-spline basis, 8 = silu, 9..11 = pad
//   grid (8 n-tiles x 192 k-chunks); chunk = 16 inputs = 192 k = 6 MFMA steps.
//   Each block: stage A(128x192k) + W(32x192k) to LDS -> 1 barrier ->
//   12 MFMA/wave -> bf16 partial[chunk][b][o].  Reduce fused with selu+layer2.
// ---------------------------------------------------------------------------

#define B_DIM   128
#define IN1     3072
#define OUT1    256
#define NB      8
#define OUT2    10

#define CI      16                 // inputs per chunk
#define NCH     (IN1 / CI)         // 192 chunks
#define KS      6                  // k-steps of 32 per chunk (16*12/32)
#define LDP     200                // padded LDS row (ushorts) for 192 k
#define BN      32                 // o-tile per block

typedef short  bf16x8 __attribute__((ext_vector_type(8)));
typedef float  f32x4  __attribute__((ext_vector_type(4)));
typedef unsigned short ushort_t;

__device__ __forceinline__ ushort_t f2bf(float f) {
    union { __hip_bfloat16 h; ushort_t u; } v;
    v.h = __float2bfloat16(f);
    return v.u;
}
__device__ __forceinline__ float bf2f(ushort_t h) {
    union { float f; unsigned int u; } v; v.u = ((unsigned int)h) << 16;
    return v.f;
}

// cardinal cubic B-spline basis (8 funcs) + silu, closed form (== Cox-de Boor
// recursion of the reference on the uniform extended grid [-2.2,2.2], h=0.4).
__device__ __forceinline__ void basis_silu(float x, float w[8], float& sil) {
    sil = x / (1.0f + __expf(-x));
    float u  = (x + 2.2f) * 2.5f;
    float uf = floorf(u);
    int   j  = (int)uf;
    float t  = u - uf;
    float omt = 1.0f - t;
    float t2 = t * t, t3 = t2 * t;
    float w0 = omt * omt * omt * (1.0f / 6.0f);
    float w1 = (3.0f * t3 - 6.0f * t2 + 4.0f) * (1.0f / 6.0f);
    float w2 = (-3.0f * t3 + 3.0f * t2 + 3.0f * t + 1.0f) * (1.0f / 6.0f);
    float w3 = t3 * (1.0f / 6.0f);
    bool valid = (u >= 0.0f) && (u < 11.0f);
#pragma unroll
    for (int g = 0; g < 8; ++g) {
        int m = g - j + 3;
        float v = (m == 0) ? w0 : (m == 1) ? w1 : (m == 2) ? w2 : (m == 3) ? w3 : 0.0f;
        w[g] = valid ? v : 0.0f;
    }
}

__device__ __forceinline__ float selu_f(float x) {
    const float scale = 1.0507009873554805f;
    const float alpha = 1.6732632423543772f;
    return (x > 0.0f) ? scale * x : scale * alpha * (__expf(x) - 1.0f);
}

// ---------------------------------------------------------------------------
// Kernel G: single-shot MFMA chunk.  512 threads (8 waves).
//   wave w: nt = w&1 (o-subtile), mg = w>>1 (m-pair) -> out 32 x 16.
// ---------------------------------------------------------------------------
__global__ __launch_bounds__(512) void kan_gemm(const float* __restrict__ x,
                                                const float* __restrict__ coef1,
                                                const float* __restrict__ sb1,
                                                const float* __restrict__ ssp1,
                                                ushort_t* __restrict__ partial) {
    __shared__ ushort_t Al[B_DIM][LDP];   // 51.2 KB
    __shared__ ushort_t Bl[BN][LDP];      // 12.8 KB
    const int tid   = threadIdx.x;
    const int o0    = blockIdx.x * BN;
    const int chunk = blockIdx.y;
    const int i0    = chunk * CI;

    // ---- stage W: 512 thr -> 32 o x 16 i (1 each); 512B runs per 16 lanes ----
    {
        const int ol = tid >> 4;
        const int ii = tid & 15;
        const size_t e = (size_t)(o0 + ol) * IN1 + (i0 + ii);
        const float4 c0 = *reinterpret_cast<const float4*>(coef1 + e * NB);
        const float4 c1 = *reinterpret_cast<const float4*>(coef1 + e * NB + 4);
        const float sspv = ssp1[e];
        const float sbv  = sb1[e];
        ushort4 pa, pb, pc;
        pa.x = f2bf(c0.x * sspv); pa.y = f2bf(c0.y * sspv);
        pa.z = f2bf(c0.z * sspv); pa.w = f2bf(c0.w * sspv);
        pb.x = f2bf(c1.x * sspv); pb.y = f2bf(c1.y * sspv);
        pb.z = f2bf(c1.z * sspv); pb.w = f2bf(c1.w * sspv);
        pc.x = f2bf(sbv); pc.y = 0; pc.z = 0; pc.w = 0;
        *reinterpret_cast<ushort4*>(&Bl[ol][ii * 12 + 0]) = pa;
        *reinterpret_cast<ushort4*>(&Bl[ol][ii * 12 + 4]) = pb;
        *reinterpret_cast<ushort4*>(&Bl[ol][ii * 12 + 8]) = pc;
    }
    // ---- stage A: 512 thr -> 128 b x 16 i (4 each) ----
    {
        const int b = tid >> 2;
        const int q = tid & 3;
        float4 xv = *reinterpret_cast<const float4*>(x + (size_t)b * IN1 + i0 + q * 4);
        float xa[4] = {xv.x, xv.y, xv.z, xv.w};
#pragma unroll
        for (int p = 0; p < 4; ++p) {
            const int ii = q * 4 + p;
            float bs[8], sil;
            basis_silu(xa[p], bs, sil);
            ushort4 pa, pb, pc;
            pa.x = f2bf(bs[0]); pa.y = f2bf(bs[1]); pa.z = f2bf(bs[2]); pa.w = f2bf(bs[3]);
            pb.x = f2bf(bs[4]); pb.y = f2bf(bs[5]); pb.z = f2bf(bs[6]); pb.w = f2bf(bs[7]);
            pc.x = f2bf(sil);   pc.y = 0;           pc.z = 0;           pc.w = 0;
            *reinterpret_cast<ushort4*>(&Al[b][ii * 12 + 0]) = pa;
            *reinterpret_cast<ushort4*>(&Al[b][ii * 12 + 4]) = pb;
            *reinterpret_cast<ushort4*>(&Al[b][ii * 12 + 8]) = pc;
        }
    }
    __syncthreads();

    // ---- MFMA: 6 k-steps, 2 m-tiles per wave ----
    const int w = tid >> 6, l = tid & 63;
    const int nt = w & 1, mg = w >> 1;
    const int row16 = l & 15, kg = (l >> 4) * 8;
    f32x4 acc0 = {0.f, 0.f, 0.f, 0.f};
    f32x4 acc1 = {0.f, 0.f, 0.f, 0.f};
#pragma unroll
    for (int ks = 0; ks < KS; ++ks) {
        bf16x8 bfrag = *reinterpret_cast<const bf16x8*>(&Bl[nt * 16 + row16][ks * 32 + kg]);
        bf16x8 a0 = *reinterpret_cast<const bf16x8*>(&Al[(mg * 2 + 0) * 16 + row16][ks * 32 + kg]);
        bf16x8 a1 = *reinterpret_cast<const bf16x8*>(&Al[(mg * 2 + 1) * 16 + row16][ks * 32 + kg]);
        acc0 = __builtin_amdgcn_mfma_f32_16x16x32_bf16(a0, bfrag, acc0, 0, 0, 0);
        acc1 = __builtin_amdgcn_mfma_f32_16x16x32_bf16(a1, bfrag, acc1, 0, 0, 0);
    }

    // ---- epilogue: bf16 partial [chunk][b][o] ----
    const size_t base = (size_t)chunk * (B_DIM * OUT1);
    const int col = o0 + nt * 16 + row16;
    const int rb  = (l >> 4) * 4;
#pragma unroll
    for (int r = 0; r < 4; ++r) {
        partial[base + (size_t)((mg * 2 + 0) * 16 + rb + r) * OUT1 + col] = f2bf(acc0[r]);
        partial[base + (size_t)((mg * 2 + 1) * 16 + rb + r) * OUT1 + col] = f2bf(acc1[r]);
    }
}

// ---------------------------------------------------------------------------
// Kernel R: reduce partials (4-way split over 1024 thr) -> h, selu, layer2.
// ---------------------------------------------------------------------------
#define CPG (NCH / 4)   // 48 chunks per group

__global__ __launch_bounds__(1024) void kan_reduce_l2(const ushort_t* __restrict__ partial,
                                                      const float* __restrict__ coef2,
                                                      const float* __restrict__ sb2,
                                                      const float* __restrict__ ssp2,
                                                      float* __restrict__ out) {
    const int b = blockIdx.x;
    const int t = threadIdx.x;
    const int o = t & 255;
    const int g = t >> 8;                    // 0..3
    const ushort_t* pp = partial + (size_t)g * CPG * (B_DIM * OUT1)
                                 + (size_t)b * OUT1 + o;
    float sum = 0.0f;
#pragma unroll 8
    for (int c = 0; c < CPG; ++c)
        sum += bf2f(pp[(size_t)c * (B_DIM * OUT1)]);

    __shared__ float hred[4][OUT1];
    hred[g][o] = sum;
    __syncthreads();
    const float hv = hred[0][o] + hred[1][o] + hred[2][o] + hred[3][o];

    const float sh = selu_f(hv);
    float w8[8], sil;
    basis_silu(sh, w8, sil);

    float accs[OUT2];
#pragma unroll
    for (int oo = 0; oo < OUT2; ++oo) {
        const float* cp = coef2 + ((size_t)oo * OUT1 + o) * NB;
        float4 c0 = *reinterpret_cast<const float4*>(cp);
        float4 c1 = *reinterpret_cast<const float4*>(cp + 4);
        float dot = w8[0] * c0.x + w8[1] * c0.y + w8[2] * c0.z + w8[3] * c0.w +
                    w8[4] * c1.x + w8[5] * c1.y + w8[6] * c1.z + w8[7] * c1.w;
        accs[oo] = sb2[oo * OUT1 + o] * sil + ssp2[oo * OUT1 + o] * dot;
    }

    __shared__ float red[16][OUT2];
    const int lane = t & 63, wv = t >> 6;
#pragma unroll
    for (int oo = 0; oo < OUT2; ++oo) {
        float v = accs[oo];
#pragma unroll
        for (int off = 32; off >= 1; off >>= 1) v += __shfl_xor(v, off, 64);
        if (lane == 0) red[wv][oo] = v;
    }
    __syncthreads();
    if (t < OUT2)
        out[b * OUT2 + t] = red[0][t] + red[1][t] + red[2][t] + red[3][t];
}

// ---------------------------------------------------------------------------
extern "C" void kernel_launch(void* const* d_in, const int* in_sizes, int n_in,
                              void* d_out, int out_size, void* d_ws, size_t ws_size,
                              hipStream_t stream) {
    const float* x     = (const float*)d_in[0];
    const float* coef1 = (const float*)d_in[1];
    const float* sb1   = (const float*)d_in[2];
    const float* ssp1  = (const float*)d_in[3];
    const float* coef2 = (const float*)d_in[4];
    const float* sb2   = (const float*)d_in[5];
    const float* ssp2  = (const float*)d_in[6];
    float* out = (float*)d_out;

    ushort_t* partial = (ushort_t*)d_ws;     // 192*128*256*2B = 12.6 MB

    kan_gemm<<<dim3(OUT1 / BN, NCH), 512, 0, stream>>>(x, coef1, sb1, ssp1, partial);
    kan_reduce_l2<<<B_DIM, 1024, 0, stream>>>(partial, coef2, sb2, ssp2, out);
}